// Round 11
// baseline (9173.400 us; speedup 1.0000x reference)
//
#include <hip/hip_runtime.h>
#include <hip/hip_bf16.h>
#include <stdint.h>
#include <stddef.h>

#define B_SZ   4096
#define U_SZ   1024
#define SEQ    5
#define TSTEPS 200
#define STEPS  204          // 5 warmup + 199 decode LSTM steps

typedef __bf16 bf16_t;
typedef __bf16 bf16x8 __attribute__((ext_vector_type(8)));
typedef float  f32x4  __attribute__((ext_vector_type(4)));

#define AS1 __attribute__((address_space(1)))
#define AS3 __attribute__((address_space(3)))

#define LOAD_LDS16(gp, lp) \
    __builtin_amdgcn_global_load_lds((const AS1 unsigned int*)(gp), \
                                     (AS3 unsigned int*)(lp), 16, 0, 0)

__device__ __forceinline__ float fsig(float x) {
    return 1.0f / (1.0f + __expf(-x));
}
__device__ __forceinline__ float ftanh(float x) {
    x = fminf(fmaxf(x, -15.0f), 15.0f);
    float e = __expf(2.0f * x);
    return (e - 1.0f) / (e + 1.0f);
}

// ---------------------------------------------------------------------------
// Pack R into bf16 panels for BK=32 staging (round-7 verbatim, VERIFIED):
//   Rp[ub:32][kb:32][c:128][slot:4][e:8], phys slot holds logical
//   k-slot = slot ^ ((c>>1)&3)  -> conflict-free ds_read_b128 + linear staging.
//   col c -> n = g*1024 + ub*32 + wc*16 + cl
// ---------------------------------------------------------------------------
__global__ void pack_R(const float* __restrict__ R, bf16_t* __restrict__ Rp) {
    int idx = blockIdx.x * 256 + threadIdx.x;   // 4,194,304 total
    int e    = idx & 7;
    int slot = (idx >> 3) & 3;                  // physical 16B slot in 64B row
    int c    = (idx >> 5) & 127;
    int kb   = (idx >> 12) & 31;
    int ub   = idx >> 17;
    int g  = (c >> 4) & 3;
    int wc = c >> 6;
    int cl = c & 15;
    int n  = g * 1024 + ub * 32 + wc * 16 + cl;
    int k  = kb * 32 + ((slot ^ ((c >> 1) & 3)) << 3) + e;  // logical k
    Rp[idx] = (bf16_t)R[(size_t)k * 4096 + n];
}

// ---------------------------------------------------------------------------
// SINGLE-PANEL block, 4 blocks/CU (occupancy attack on the sync-bound plateau):
//   grid 1024 = 32 p x 32 G = exactly 4 blocks/CU, __launch_bounds__(256,4).
//   Per block: 128 rows x 128 cols (1 panel), acc 64 f32/lane.
//   BK=32 K-loop, ONE raw barrier + ONE counted vmcnt(2) per kb:
//     top: s_waitcnt vmcnt(2)   <- A(kb),B(kb) landed; A(kb+1) (newest 2
//                                  loads) stays in flight
//          s_barrier (raw, no drain)
//     STAGE_B(kb+1) -> parity   (1-iter cover, L2-hit)
//     STAGE_A(kb+2) -> %3 slot  (2-iter cover, cross-L2 h)
//     8 ds_read_b128 -> frags ; 16 MFMA (setprio)
//   A triple 3x8KB + B double 2x8KB = 40 KB -> 4 blocks/CU x 40 = 160 KB.
//   lsX -> registers + __shfl (r5-verified).  Buffer-overwrite safety: the
//   slot written this iter was last read at iter kb-1, consumed before that
//   iter's MFMAs which precede this barrier.
// ---------------------------------------------------------------------------
__global__ __launch_bounds__(256, 4)
void lstm_step(const bf16_t* __restrict__ hin,
               bf16_t* __restrict__ hout,
               float* __restrict__ cst,
               const bf16_t* __restrict__ Rp,
               const float* __restrict__ Wx,     // (4096,)
               const float* __restrict__ bias,   // (4096,)
               const float* __restrict__ w1,     // (1024,)
               const float* __restrict__ b1,
               const float* __restrict__ w2,
               const float* __restrict__ b2,
               const float* __restrict__ inputs, // [4096,5]
               float* __restrict__ praw,         // 3*4096
               float* __restrict__ out,          // [4096,200]
               int t)
{
    __shared__ __align__(16) bf16_t lsA[3][4096];        // 24 KB (triple)
    __shared__ __align__(16) bf16_t lsB[2][4096];        // 16 KB (double)

    const int tid  = threadIdx.x;
    const int wave = tid >> 6;
    const int lane = tid & 63;
    // ---- 2-D XCD tiling (r10-verified traffic win): xcd = bid&7 owns
    //      p in [(xcd&3)*8, +8), G in [(xcd>>2)*16, +16) ----
    const int bid  = blockIdx.x + 32 * blockIdx.y;   // x fastest
    const int xcd  = bid & 7;
    const int j    = bid >> 3;                       // 0..127 within XCD
    const int p    = (xcd & 3) * 8 + (j & 7);        // 0..31 (single panel)
    const int G    = (xcd >> 2) * 16 + (j >> 3);     // 0..31
    const int l15  = lane & 15;
    const int quad = lane >> 4;
    const int rbase = (wave >> 1) * 64;
    const int wc    = wave & 1;
    const int a_kk32 = (((lane & 3) ^ ((lane >> 3) & 3)) << 3);  // r7-verified
    const int sw32   = ((quad ^ ((l15 >> 1) & 3)) << 3);         // r7-verified

    float*       pr_acc  = praw + (size_t)(t % 3) * B_SZ;
    const float* pr_read = praw + (size_t)((t + 2) % 3) * B_SZ;
    float*       pr_zero = praw + (size_t)((t + 1) % 3) * B_SZ;

    const bf16_t* Ap = hin + (size_t)G * 128 * U_SZ;
    const bf16_t* Bp = Rp + (size_t)p * 131072;

    // ---- stage helpers (r7-verified patterns, single panel) ----
    auto STAGE_A = [&](int ksrc, int abuf) {
        #pragma unroll
        for (int i = 0; i < 2; ++i) {
            int brow = i * 64 + wave * 16;
            LOAD_LDS16(Ap + (size_t)(brow + (lane >> 2)) * U_SZ
                          + ksrc * 32 + a_kk32,
                       &lsA[abuf][brow * 32]);
        }
    };
    auto STAGE_B = [&](int ksrc, int bbuf) {
        #pragma unroll
        for (int i = 0; i < 2; ++i) {
            int chunk = wave * 2 + i;
            LOAD_LDS16(Bp + (size_t)ksrc * 4096 + chunk * 512 + lane * 8,
                       &lsB[bbuf][chunk * 512]);
        }
    };

    // ---- pipeline fill: A(0),B(0) -> slot 0; A(1) -> slot 1 ----
    STAGE_A(0, 0); STAGE_B(0, 0); STAGE_A(1, 1);

    // ---- prologue: x in-register (r5-verified xw+shfl pattern) ----
    float xw;
    {
        int row = G * 128 + rbase + lane;
        float x;
        if (t < SEQ) {
            x = inputs[row * SEQ + t];
        } else {
            float x1 = fmaxf(pr_read[row] + b1[0], 0.f);
            x = (t == SEQ) ? x1 : x1 * w2[0] + b2[0];
            if (p == 0 && (wave & 1) == 0)
                out[(size_t)row * TSTEPS + (t - SEQ)] = x;
        }
        xw = x;
        if (p == 0 && (wave & 1) == 0) pr_zero[row] = 0.f;
    }

    // ---- K-loop: 32 steps of BK=32, one barrier + one counted vmcnt each ----
    f32x4 acc[4][4] = {};
    int ap = 0;                                  // A slot of current kb (kb%3)

    #pragma clang loop unroll(disable)
    for (int kb = 0; kb < 32; ++kb) {
        // A(kb)+B(kb) landed; A(kb+1) = newest 2 loads stays in flight
        asm volatile("s_waitcnt vmcnt(2)" ::: "memory");
        __builtin_amdgcn_sched_barrier(0);
        __builtin_amdgcn_s_barrier();
        __builtin_amdgcn_sched_barrier(0);

        if (kb < 31) STAGE_B(kb + 1, (kb + 1) & 1);
        int ap2 = ap + 2; if (ap2 >= 3) ap2 -= 3;
        if (kb < 30) STAGE_A(kb + 2, ap2);

        // fragments -> regs (compiler inserts fine-grained lgkmcnt)
        bf16x8 af[4], bfr[4];
        #pragma unroll
        for (int mi = 0; mi < 4; ++mi)
            af[mi] = *(const bf16x8*)
                &lsA[ap][(rbase + mi * 16 + l15) * 32 + sw32];
        #pragma unroll
        for (int ni = 0; ni < 4; ++ni)
            bfr[ni] = *(const bf16x8*)
                &lsB[kb & 1][(wc * 64 + ni * 16 + l15) * 32 + sw32];

        __builtin_amdgcn_s_setprio(1);
        #pragma unroll
        for (int mi = 0; mi < 4; ++mi)
            #pragma unroll
            for (int ni = 0; ni < 4; ++ni)
                acc[mi][ni] = __builtin_amdgcn_mfma_f32_16x16x32_bf16(
                    af[mi], bfr[ni], acc[mi][ni], 0, 0, 0);
        __builtin_amdgcn_s_setprio(0);

        ap = ap + 1; if (ap >= 3) ap = 0;
    }

    // ---- epilogue: gates (gate index = ni), c RMW global, h write, pred ----
    const int uu = p * 32 + wc * 16 + l15;
    float g_b[4], g_w[4];
    #pragma unroll
    for (int g = 0; g < 4; ++g) {
        g_b[g] = bias[g * 1024 + uu];
        g_w[g] = Wx[g * 1024 + uu];
    }
    const float w1u = w1[uu];
    const bool do_pred = (t >= SEQ - 1);

    #pragma unroll
    for (int mi = 0; mi < 4; ++mi) {
        #pragma unroll
        for (int r = 0; r < 4; ++r) {
            int rl   = rbase + mi * 16 + quad * 4 + r;
            int brow = G * 128 + rl;
            float xv = __shfl(xw, mi * 16 + quad * 4 + r);
            float zi = acc[mi][0][r] + g_b[0] + xv * g_w[0];
            float zf = acc[mi][1][r] + g_b[1] + xv * g_w[1];
            float zg = acc[mi][2][r] + g_b[2] + xv * g_w[2];
            float zo = acc[mi][3][r] + g_b[3] + xv * g_w[3];
            float ig = fsig(zi), fg = fsig(zf);
            float gg = ftanh(zg), og = fsig(zo);
            size_t off = (size_t)brow * U_SZ + uu;
            float cn = fg * cst[off] + ig * gg;
            cst[off] = cn;
            float hv = og * ftanh(cn);
            hout[off] = (bf16_t)hv;
            float ps = hv * w1u;
            if (do_pred) {
                ps += __shfl_xor(ps, 1);
                ps += __shfl_xor(ps, 2);
                ps += __shfl_xor(ps, 4);
                ps += __shfl_xor(ps, 8);
                if (l15 == 0) atomicAdd(&pr_acc[brow], ps);
            }
        }
    }
}

// final output slot 199 from praw of step 203 (203 % 3 == 2)
__global__ void pred_final(const float* __restrict__ praw,
                           const float* __restrict__ b1,
                           const float* __restrict__ w2,
                           const float* __restrict__ b2,
                           float* __restrict__ out)
{
    int row = blockIdx.x * 256 + threadIdx.x;
    float x1 = fmaxf(praw[2 * B_SZ + row] + b1[0], 0.f);
    out[(size_t)row * TSTEPS + 199] = x1 * w2[0] + b2[0];
}

extern "C" void kernel_launch(void* const* d_in, const int* in_sizes, int n_in,
                              void* d_out, int out_size, void* d_ws, size_t ws_size,
                              hipStream_t stream) {
    const float* inputs = (const float*)d_in[0];   // [4096,5,1]
    const float* Wx     = (const float*)d_in[1];   // [1,4096]
    const float* R      = (const float*)d_in[2];   // [1024,4096]
    const float* bias   = (const float*)d_in[3];   // [4096]
    const float* w1     = (const float*)d_in[4];   // [1024,1]
    const float* b1     = (const float*)d_in[5];
    const float* w2     = (const float*)d_in[6];
    const float* b2     = (const float*)d_in[7];
    float* out = (float*)d_out;

    char* ws = (char*)d_ws;
    const size_t RP_BYTES = (size_t)32 * 131072 * 2;          // 8 MB
    const size_t H_BYTES  = (size_t)B_SZ * U_SZ * 2;          // 8 MB
    const size_t C_BYTES  = (size_t)B_SZ * U_SZ * 4;          // 16 MB
    bf16_t* Rp   = (bf16_t*)ws;                ws += RP_BYTES;
    bf16_t* h0   = (bf16_t*)ws;                ws += H_BYTES;
    bf16_t* h1   = (bf16_t*)ws;                ws += H_BYTES;
    float*  cbuf = (float*)ws;                 ws += C_BYTES;
    float*  praw = (float*)ws;                 ws += 3 * B_SZ * 4;
    bf16_t* hb[2] = {h0, h1};

    hipMemsetAsync(h0, 0, H_BYTES, stream);
    hipMemsetAsync(cbuf, 0, C_BYTES, stream);
    hipMemsetAsync(praw, 0, 3 * B_SZ * 4, stream);

    pack_R<<<16384, 256, 0, stream>>>(R, Rp);

    dim3 grid(32, 32);   // 1024 single-panel blocks = exactly 4/CU
    int cur = 0;
    for (int t = 0; t < STEPS; ++t) {
        lstm_step<<<grid, 256, 0, stream>>>(hb[cur], hb[1 - cur], cbuf, Rp,
                                            Wx, bias, w1, b1, w2, b2,
                                            inputs, praw, out, t);
        cur ^= 1;
    }
    pred_final<<<16, 256, 0, stream>>>(praw, b1, w2, b2, out);
}